// Round 7
// baseline (333.714 us; speedup 1.0000x reference)
//
#include <hip/hip_runtime.h>

typedef __bf16 bf16x8 __attribute__((ext_vector_type(8)));
typedef float  f32x4  __attribute__((ext_vector_type(4)));
typedef unsigned int u32x4 __attribute__((ext_vector_type(4)));

#define MFMA16 __builtin_amdgcn_mfma_f32_16x16x32_bf16

// ---- LDS layout ----
// unsigned short indices:
#define XT_S 0        // Xt[60][40] bf16 (cols 30..39 zero)
#define A_S  2400     // A[60][72] bf16 (cols 60..63 zero, 64..71 unused)
#define B_S  6720     // B[60][72] bf16
#define HT_S 11040    // 4 waves * [16][72] bf16
// float indices (short idx / 2):
#define EB_F 7824     // Ebar[60][20] f32
#define O_F  9024     // O[24] f32
#define NSH  18096    // total shorts = 36192 B (35.3 KB -> 4 blocks/CU)

__device__ __forceinline__ float bl(unsigned u){ return __builtin_bit_cast(float, u << 16); }
__device__ __forceinline__ float bh(unsigned u){ return __builtin_bit_cast(float, u & 0xffff0000u); }
__device__ __forceinline__ unsigned short bits16(float x){ return __builtin_bit_cast(unsigned short, (__bf16)x); }

__device__ __forceinline__ bf16x8 addrelu(u32x4 a, u32x4 b){
    bf16x8 o;
    #pragma unroll
    for (int k = 0; k < 4; ++k){
        const float lo = bl(a[k]) + bl(b[k]);
        const float hi = bh(a[k]) + bh(b[k]);
        o[2*k]   = (__bf16)fmaxf(lo, 0.f);
        o[2*k+1] = (__bf16)fmaxf(hi, 0.f);
    }
    return o;
}

__global__ __launch_bounds__(256, 2)
void innet_kernel(const float* __restrict__ x,
                  const float* __restrict__ fr_w1, const float* __restrict__ fr_b1,
                  const float* __restrict__ fr_w2, const float* __restrict__ fr_b2,
                  const float* __restrict__ fr_w3, const float* __restrict__ fr_b3,
                  const float* __restrict__ fo_w1, const float* __restrict__ fo_b1,
                  const float* __restrict__ fo_w2, const float* __restrict__ fo_b2,
                  const float* __restrict__ fo_w3, const float* __restrict__ fo_b3,
                  float* __restrict__ out)
{
    __shared__ __align__(16) unsigned short ss[NSH];
    float* sf = (float*)ss;

    const int b      = blockIdx.x;
    const int tid    = threadIdx.x;
    const int lane15 = tid & 15;
    const int g4     = (tid >> 4) & 3;
    const int w      = tid >> 6;
    const int wbS    = HT_S + w * 1152;      // per-wave Ht base (short idx)

    // ---- phase 0: stage x -> Xt bf16 [p][f], zero pads/EB/O ----
    const float* xb = x + b * 1800;
    for (int i = tid; i < 1800; i += 256){
        const int f = i / 60, p = i - f * 60;
        ss[XT_S + p * 40 + f] = bits16(xb[i]);
    }
    for (int i = tid; i < 600; i += 256){
        const int p = i / 10;
        ss[XT_S + p * 40 + 30 + (i - p * 10)] = 0;
    }
    for (int i = tid; i < 1200; i += 256) sf[EB_F + i] = 0.f;
    if (tid < 24) sf[O_F + tid] = 0.f;
    __syncthreads();

    // ---- phase 1: A/B panels via MFMA. wave w = M-tile rows [16w,16w+16) ----
    {
        bf16x8 w1af[4], w1bf[4];
        float b1v[4];
        #pragma unroll
        for (int n = 0; n < 4; ++n){
            const int col = n * 16 + lane15;
            const bool cvv = col < 60;
            b1v[n] = cvv ? fr_b1[col] : 0.f;
            #pragma unroll
            for (int j = 0; j < 8; ++j){
                const int f = g4 * 8 + j;
                w1af[n][j] = (__bf16)((f < 30 && cvv) ? fr_w1[f * 60 + col] : 0.f);
                w1bf[n][j] = (__bf16)((f < 30 && cvv) ? fr_w1[(30 + f) * 60 + col] : 0.f);
            }
        }
        const int pr_ = w * 16 + lane15;
        const u32x4 ux = *(const u32x4*)&ss[XT_S + pr_ * 40 + g4 * 8];
        const bf16x8 xa = __builtin_bit_cast(bf16x8, ux);
        const f32x4 z = {0.f, 0.f, 0.f, 0.f};
        f32x4 aA0 = MFMA16(xa, w1af[0], z, 0, 0, 0);
        f32x4 aA1 = MFMA16(xa, w1af[1], z, 0, 0, 0);
        f32x4 aA2 = MFMA16(xa, w1af[2], z, 0, 0, 0);
        f32x4 aA3 = MFMA16(xa, w1af[3], z, 0, 0, 0);
        f32x4 aB0 = MFMA16(xa, w1bf[0], z, 0, 0, 0);
        f32x4 aB1 = MFMA16(xa, w1bf[1], z, 0, 0, 0);
        f32x4 aB2 = MFMA16(xa, w1bf[2], z, 0, 0, 0);
        f32x4 aB3 = MFMA16(xa, w1bf[3], z, 0, 0, 0);
        #pragma unroll
        for (int reg = 0; reg < 4; ++reg){
            const int p = w * 16 + g4 * 4 + reg;
            if (p < 60){
                ss[A_S + p * 72 +      lane15] = bits16(aA0[reg] + b1v[0]);
                ss[A_S + p * 72 + 16 + lane15] = bits16(aA1[reg] + b1v[1]);
                ss[A_S + p * 72 + 32 + lane15] = bits16(aA2[reg] + b1v[2]);
                ss[A_S + p * 72 + 48 + lane15] = bits16(aA3[reg] + b1v[3]);
                ss[B_S + p * 72 +      lane15] = bits16(aB0[reg]);
                ss[B_S + p * 72 + 16 + lane15] = bits16(aB1[reg]);
                ss[B_S + p * 72 + 32 + lane15] = bits16(aB2[reg]);
                ss[B_S + p * 72 + 48 + lane15] = bits16(aB3[reg]);
            }
        }
    }
    __syncthreads();

    // ---- fr layer-2/3 weight fragments (registers) ----
    bf16x8 w2f[4][2], w3f[2][2];
    float b2v[4], b3v[2];
    #pragma unroll
    for (int n = 0; n < 4; ++n){
        const int col = n * 16 + lane15;
        b2v[n] = (col < 60) ? fr_b2[col] : 0.f;
        #pragma unroll
        for (int c = 0; c < 2; ++c){
            #pragma unroll
            for (int j = 0; j < 8; ++j){
                const int k = c * 32 + g4 * 8 + j;
                w2f[n][c][j] = (__bf16)((k < 60 && col < 60) ? fr_w2[k * 60 + col] : 0.f);
            }
        }
    }
    #pragma unroll
    for (int n = 0; n < 2; ++n){
        const int col = n * 16 + lane15;
        b3v[n] = (col < 20) ? fr_b3[col] : 0.f;
        #pragma unroll
        for (int c = 0; c < 2; ++c){
            #pragma unroll
            for (int j = 0; j < 8; ++j){
                const int k = c * 32 + g4 * 8 + j;
                w3f[n][c][j] = (__bf16)((k < 60 && col < 20) ? fr_w3[k * 20 + col] : 0.f);
            }
        }
    }

    auto writeHt = [&](const f32x4& a, float bias, int n){
        #pragma unroll
        for (int reg = 0; reg < 4; ++reg)
            ss[wbS + (g4 * 4 + reg) * 72 + n * 16 + lane15] = bits16(fmaxf(a[reg] + bias, 0.f));
    };
    auto scat = [&](const f32x4& ae, int n, int q0){
        const int col = n * 16 + lane15;
        const bool cv = (col < 20);
        float run = 0.f;
        int pr = (q0 + g4 * 4) / 60;
        #pragma unroll
        for (int reg = 0; reg < 4; ++reg){
            const int qq = q0 + g4 * 4 + reg;
            const int rr = qq / 60;
            const int si = qq - rr * 60;
            float e = 0.f;
            if (cv && si != rr) e = fmaxf(ae[reg] + b3v[n], 0.f);
            if (rr != pr){
                if (cv && run != 0.f) atomicAdd(&sf[EB_F + pr * 20 + col], run);
                run = 0.f; pr = rr;
            }
            run += e;
        }
        if (cv && run != 0.f) atomicAdd(&sf[EB_F + pr * 20 + col], run);
    };

    // ---- phase 2: pair loop over 225 16-row tiles of the 60x60 grid ----
    #pragma unroll 1
    for (int t = w; t < 225; t += 4){
        const int q0 = t * 16;
        const int q  = q0 + lane15;
        const int r  = q / 60;
        const int si = q - r * 60;
        const int ba = A_S + r  * 72 + g4 * 8;
        const int bb = B_S + si * 72 + g4 * 8;
        const u32x4 ra0 = *(const u32x4*)&ss[ba];
        const u32x4 rb0 = *(const u32x4*)&ss[bb];
        const u32x4 ra1 = *(const u32x4*)&ss[ba + 32];
        const u32x4 rb1 = *(const u32x4*)&ss[bb + 32];
        const bf16x8 af0 = addrelu(ra0, rb0);
        const bf16x8 af1 = addrelu(ra1, rb1);

        f32x4 acc0 = {0.f,0.f,0.f,0.f}, acc1 = {0.f,0.f,0.f,0.f};
        f32x4 acc2 = {0.f,0.f,0.f,0.f}, acc3 = {0.f,0.f,0.f,0.f};
        acc0 = MFMA16(af0, w2f[0][0], acc0, 0, 0, 0);
        acc1 = MFMA16(af0, w2f[1][0], acc1, 0, 0, 0);
        acc2 = MFMA16(af0, w2f[2][0], acc2, 0, 0, 0);
        acc3 = MFMA16(af0, w2f[3][0], acc3, 0, 0, 0);
        acc0 = MFMA16(af1, w2f[0][1], acc0, 0, 0, 0);
        acc1 = MFMA16(af1, w2f[1][1], acc1, 0, 0, 0);
        acc2 = MFMA16(af1, w2f[2][1], acc2, 0, 0, 0);
        acc3 = MFMA16(af1, w2f[3][1], acc3, 0, 0, 0);

        writeHt(acc0, b2v[0], 0);
        writeHt(acc1, b2v[1], 1);
        writeHt(acc2, b2v[2], 2);
        writeHt(acc3, b2v[3], 3);
        asm volatile("s_waitcnt lgkmcnt(0)" ::: "memory");
        __builtin_amdgcn_sched_barrier(0);

        const u32x4 h0 = *(const u32x4*)&ss[wbS + lane15 * 72 + g4 * 8];
        const u32x4 h1 = *(const u32x4*)&ss[wbS + lane15 * 72 + 32 + g4 * 8];
        const bf16x8 hf0 = __builtin_bit_cast(bf16x8, h0);
        const bf16x8 hf1 = __builtin_bit_cast(bf16x8, h1);
        f32x4 ae0 = {0.f,0.f,0.f,0.f}, ae1 = {0.f,0.f,0.f,0.f};
        ae0 = MFMA16(hf0, w3f[0][0], ae0, 0, 0, 0);
        ae1 = MFMA16(hf0, w3f[1][0], ae1, 0, 0, 0);
        ae0 = MFMA16(hf1, w3f[0][1], ae0, 0, 0, 0);
        ae1 = MFMA16(hf1, w3f[1][1], ae1, 0, 0, 0);

        scat(ae0, 0, q0);
        scat(ae1, 1, q0);
    }
    __syncthreads();

    // ---- phase 5: output MLP via MFMA. wave w = particle rows [16w,16w+16) ----
    {
        const int p5 = w * 16 + lane15;
        const int pe = (p5 < 60) ? p5 : 0;
        // A-frag for C = [x_p(30), Ebar_p(20)] padded to 64
        const u32x4 uc0 = *(const u32x4*)&ss[XT_S + pe * 40 + g4 * 8];
        bf16x8 ca0 = __builtin_bit_cast(bf16x8, uc0);
        if (g4 == 3){
            ca0[6] = (__bf16)sf[EB_F + pe * 20 + 0];
            ca0[7] = (__bf16)sf[EB_F + pe * 20 + 1];
        }
        bf16x8 ca1;
        #pragma unroll
        for (int j = 0; j < 8; ++j){
            const int d = 2 + g4 * 8 + j;
            ca1[j] = (d < 20) ? (__bf16)sf[EB_F + pe * 20 + d] : (__bf16)0.f;
        }
        // fo_w1 frags
        bf16x8 wf[4][2]; float bv[4];
        #pragma unroll
        for (int n = 0; n < 4; ++n){
            const int col = n * 16 + lane15;
            bv[n] = (col < 60) ? fo_b1[col] : 0.f;
            #pragma unroll
            for (int c = 0; c < 2; ++c){
                #pragma unroll
                for (int j = 0; j < 8; ++j){
                    const int k = c * 32 + g4 * 8 + j;
                    wf[n][c][j] = (__bf16)((k < 50 && col < 60) ? fo_w1[k * 60 + col] : 0.f);
                }
            }
        }
        f32x4 g0 = {0.f,0.f,0.f,0.f}, g1 = {0.f,0.f,0.f,0.f};
        f32x4 g2 = {0.f,0.f,0.f,0.f}, g3 = {0.f,0.f,0.f,0.f};
        g0 = MFMA16(ca0, wf[0][0], g0, 0, 0, 0);
        g1 = MFMA16(ca0, wf[1][0], g1, 0, 0, 0);
        g2 = MFMA16(ca0, wf[2][0], g2, 0, 0, 0);
        g3 = MFMA16(ca0, wf[3][0], g3, 0, 0, 0);
        g0 = MFMA16(ca1, wf[0][1], g0, 0, 0, 0);
        g1 = MFMA16(ca1, wf[1][1], g1, 0, 0, 0);
        g2 = MFMA16(ca1, wf[2][1], g2, 0, 0, 0);
        g3 = MFMA16(ca1, wf[3][1], g3, 0, 0, 0);
        writeHt(g0, bv[0], 0); writeHt(g1, bv[1], 1);
        writeHt(g2, bv[2], 2); writeHt(g3, bv[3], 3);
        asm volatile("s_waitcnt lgkmcnt(0)" ::: "memory");
        __builtin_amdgcn_sched_barrier(0);
        {
            const u32x4 h0 = *(const u32x4*)&ss[wbS + lane15 * 72 + g4 * 8];
            const u32x4 h1 = *(const u32x4*)&ss[wbS + lane15 * 72 + 32 + g4 * 8];
            const bf16x8 hf0 = __builtin_bit_cast(bf16x8, h0);
            const bf16x8 hf1 = __builtin_bit_cast(bf16x8, h1);
            // fo_w2 frags (reuse wf)
            #pragma unroll
            for (int n = 0; n < 4; ++n){
                const int col = n * 16 + lane15;
                bv[n] = (col < 60) ? fo_b2[col] : 0.f;
                #pragma unroll
                for (int c = 0; c < 2; ++c){
                    #pragma unroll
                    for (int j = 0; j < 8; ++j){
                        const int k = c * 32 + g4 * 8 + j;
                        wf[n][c][j] = (__bf16)((k < 60 && col < 60) ? fo_w2[k * 60 + col] : 0.f);
                    }
                }
            }
            g0 = (f32x4){0.f,0.f,0.f,0.f}; g1 = (f32x4){0.f,0.f,0.f,0.f};
            g2 = (f32x4){0.f,0.f,0.f,0.f}; g3 = (f32x4){0.f,0.f,0.f,0.f};
            g0 = MFMA16(hf0, wf[0][0], g0, 0, 0, 0);
            g1 = MFMA16(hf0, wf[1][0], g1, 0, 0, 0);
            g2 = MFMA16(hf0, wf[2][0], g2, 0, 0, 0);
            g3 = MFMA16(hf0, wf[3][0], g3, 0, 0, 0);
            g0 = MFMA16(hf1, wf[0][1], g0, 0, 0, 0);
            g1 = MFMA16(hf1, wf[1][1], g1, 0, 0, 0);
            g2 = MFMA16(hf1, wf[2][1], g2, 0, 0, 0);
            g3 = MFMA16(hf1, wf[3][1], g3, 0, 0, 0);
            writeHt(g0, bv[0], 0); writeHt(g1, bv[1], 1);
            writeHt(g2, bv[2], 2); writeHt(g3, bv[3], 3);
        }
        asm volatile("s_waitcnt lgkmcnt(0)" ::: "memory");
        __builtin_amdgcn_sched_barrier(0);
        {
            const u32x4 h0 = *(const u32x4*)&ss[wbS + lane15 * 72 + g4 * 8];
            const u32x4 h1 = *(const u32x4*)&ss[wbS + lane15 * 72 + 32 + g4 * 8];
            const bf16x8 hf0 = __builtin_bit_cast(bf16x8, h0);
            const bf16x8 hf1 = __builtin_bit_cast(bf16x8, h1);
            // fo_w3 frags (24 cols -> 2 N-tiles)
            bf16x8 w3o[2][2]; float bv3[2];
            #pragma unroll
            for (int n = 0; n < 2; ++n){
                const int col = n * 16 + lane15;
                bv3[n] = (col < 24) ? fo_b3[col] : 0.f;
                #pragma unroll
                for (int c = 0; c < 2; ++c){
                    #pragma unroll
                    for (int j = 0; j < 8; ++j){
                        const int k = c * 32 + g4 * 8 + j;
                        w3o[n][c][j] = (__bf16)((k < 60 && col < 24) ? fo_w3[k * 24 + col] : 0.f);
                    }
                }
            }
            f32x4 o0 = {0.f,0.f,0.f,0.f}, o1 = {0.f,0.f,0.f,0.f};
            o0 = MFMA16(hf0, w3o[0][0], o0, 0, 0, 0);
            o1 = MFMA16(hf0, w3o[1][0], o1, 0, 0, 0);
            o0 = MFMA16(hf1, w3o[0][1], o0, 0, 0, 0);
            o1 = MFMA16(hf1, w3o[1][1], o1, 0, 0, 0);
            #pragma unroll
            for (int n = 0; n < 2; ++n){
                const f32x4 on = (n == 0) ? o0 : o1;
                float ssum = 0.f;
                #pragma unroll
                for (int reg = 0; reg < 4; ++reg){
                    const int p = w * 16 + g4 * 4 + reg;
                    if (p < 60) ssum += fmaxf(on[reg] + bv3[n], 0.f);
                }
                ssum += __shfl_xor(ssum, 16);
                ssum += __shfl_xor(ssum, 32);
                if (g4 == 0){
                    const int col = n * 16 + lane15;
                    if (col < 24) atomicAdd(&sf[O_F + col], ssum);
                }
            }
        }
    }
    __syncthreads();
    if (tid < 24) out[(size_t)b * 24 + tid] = sf[O_F + tid];
}

extern "C" void kernel_launch(void* const* d_in, const int* in_sizes, int n_in,
                              void* d_out, int out_size, void* d_ws, size_t ws_size,
                              hipStream_t stream) {
    const float* x      = (const float*)d_in[0];
    const float* fr_w1  = (const float*)d_in[1];
    const float* fr_b1  = (const float*)d_in[2];
    const float* fr_w2  = (const float*)d_in[3];
    const float* fr_b2  = (const float*)d_in[4];
    const float* fr_w3  = (const float*)d_in[5];
    const float* fr_b3  = (const float*)d_in[6];
    const float* fo_w1  = (const float*)d_in[7];
    const float* fo_b1  = (const float*)d_in[8];
    const float* fo_w2  = (const float*)d_in[9];
    const float* fo_b2  = (const float*)d_in[10];
    const float* fo_w3  = (const float*)d_in[11];
    const float* fo_b3  = (const float*)d_in[12];
    float* out = (float*)d_out;

    const int B = in_sizes[0] / 1800;
    innet_kernel<<<dim3(B), dim3(256), 0, stream>>>(
        x, fr_w1, fr_b1, fr_w2, fr_b2, fr_w3, fr_b3,
        fo_w1, fo_b1, fo_w2, fo_b2, fo_w3, fo_b3, out);
}

// Round 9
// 249.270 us; speedup vs baseline: 1.3388x; 1.3388x over previous
//
#include <hip/hip_runtime.h>

typedef __bf16 bf16x8 __attribute__((ext_vector_type(8)));
typedef __bf16 bf16x4 __attribute__((ext_vector_type(4)));
typedef float  f32x4  __attribute__((ext_vector_type(4)));
typedef unsigned int u32x4 __attribute__((ext_vector_type(4)));
typedef unsigned int u32x2 __attribute__((ext_vector_type(2)));
typedef short s16x4 __attribute__((ext_vector_type(4)));

#define MFMA32 __builtin_amdgcn_mfma_f32_16x16x32_bf16

// K=16 MFMA, hazard-safe: intrinsic if available (compiler inserts wait-states),
// else nop-padded inline asm.
__device__ __forceinline__ f32x4 mfma_k16(const bf16x4& a, const bf16x4& b, f32x4 c){
#if __has_builtin(__builtin_amdgcn_mfma_f32_16x16x16bf16_1k)
    return __builtin_amdgcn_mfma_f32_16x16x16bf16_1k(
        __builtin_bit_cast(s16x4, a), __builtin_bit_cast(s16x4, b), c, 0, 0, 0);
#else
    asm volatile("s_nop 1\n\t"
                 "v_mfma_f32_16x16x16_bf16 %0, %1, %2, %0\n\t"
                 "s_nop 7\n\t"
                 "s_nop 7"
                 : "+v"(c)
                 : "v"(__builtin_bit_cast(u32x2, a)), "v"(__builtin_bit_cast(u32x2, b)));
    return c;
#endif
}

// ---- LDS layout ----
// short indices:
#define XT_S 0        // Xt[60][40] bf16 (cols 30..39 zero)
#define A_S  2400     // A[64][72] bf16 (col60=1.0, 61..63=0, rows 60..63=0)
#define B_S  7008     // B[64][72] bf16 (cols 60..63=0, rows 60..63=0)
// float indices:
#define EB_F 5808     // Ebar[60][20] f32   (short 11616)
#define O_F  7008     // O[24] f32
#define NSH  14064    // 28128 B

__device__ __forceinline__ float bl(unsigned u){ return __builtin_bit_cast(float, u << 16); }
__device__ __forceinline__ float bh(unsigned u){ return __builtin_bit_cast(float, u & 0xffff0000u); }
__device__ __forceinline__ unsigned short bits16(float x){ return __builtin_bit_cast(unsigned short, (__bf16)x); }

__device__ __forceinline__ bf16x8 addrelu(u32x4 a, u32x4 b){
    bf16x8 o;
    #pragma unroll
    for (int k = 0; k < 4; ++k){
        const float lo = bl(a[k]) + bl(b[k]);
        const float hi = bh(a[k]) + bh(b[k]);
        o[2*k]   = (__bf16)fmaxf(lo, 0.f);
        o[2*k+1] = (__bf16)fmaxf(hi, 0.f);
    }
    return o;
}

__device__ __forceinline__ bf16x4 relupack(const f32x4& d){
    bf16x4 o;
    o[0] = (__bf16)fmaxf(d[0], 0.f);
    o[1] = (__bf16)fmaxf(d[1], 0.f);
    o[2] = (__bf16)fmaxf(d[2], 0.f);
    o[3] = (__bf16)fmaxf(d[3], 0.f);
    return o;
}

__global__ __launch_bounds__(256, 2)
void innet_kernel(const float* __restrict__ x,
                  const float* __restrict__ fr_w1, const float* __restrict__ fr_b1,
                  const float* __restrict__ fr_w2, const float* __restrict__ fr_b2,
                  const float* __restrict__ fr_w3, const float* __restrict__ fr_b3,
                  const float* __restrict__ fo_w1, const float* __restrict__ fo_b1,
                  const float* __restrict__ fo_w2, const float* __restrict__ fo_b2,
                  const float* __restrict__ fo_w3, const float* __restrict__ fo_b3,
                  float* __restrict__ out)
{
    __shared__ __align__(16) unsigned short ss[NSH];
    float* sf = (float*)ss;

    const int b      = blockIdx.x;
    const int tid    = threadIdx.x;
    const int lane15 = tid & 15;
    const int g4     = (tid >> 4) & 3;
    const int w      = tid >> 6;

    // ---- phase 0: stage x -> Xt bf16 [p][f]; zero pads / EB / O ----
    const float* xb = x + b * 1800;
    for (int i = tid; i < 1800; i += 256){
        const int f = i / 60, p = i - f * 60;
        ss[XT_S + p * 40 + f] = bits16(xb[i]);
    }
    for (int i = tid; i < 600; i += 256){
        const int p = i / 10;
        ss[XT_S + p * 40 + 30 + (i - p * 10)] = 0;
    }
    for (int i = tid; i < 576; i += 256){           // panel rows 60..63 = 0
        const int arr = i / 288, rem = i - arr * 288;
        ss[(arr ? B_S : A_S) + 60 * 72 + rem] = 0;
    }
    for (int i = tid; i < 1200; i += 256) sf[EB_F + i] = 0.f;
    if (tid < 24) sf[O_F + tid] = 0.f;
    __syncthreads();

    // ---- phase 1: A/B panels via MFMA (16x16x32). wave w = rows [16w,16w+16) ----
    {
        bf16x8 w1af[4], w1bf[4];
        float b1v[4];
        #pragma unroll
        for (int n = 0; n < 4; ++n){
            const int col = n * 16 + lane15;
            const bool cvv = col < 60;
            b1v[n] = cvv ? fr_b1[col] : ((col == 60) ? 1.0f : 0.0f);  // col60 of A = bias-1 row
            #pragma unroll
            for (int j = 0; j < 8; ++j){
                const int f = g4 * 8 + j;
                w1af[n][j] = (__bf16)((f < 30 && cvv) ? fr_w1[f * 60 + col] : 0.f);
                w1bf[n][j] = (__bf16)((f < 30 && cvv) ? fr_w1[(30 + f) * 60 + col] : 0.f);
            }
        }
        const int pr_ = w * 16 + lane15;
        const u32x4 ux = *(const u32x4*)&ss[XT_S + pr_ * 40 + g4 * 8];
        const bf16x8 xa = __builtin_bit_cast(bf16x8, ux);
        const f32x4 z = {0.f, 0.f, 0.f, 0.f};
        f32x4 aA0 = MFMA32(xa, w1af[0], z, 0, 0, 0);
        f32x4 aA1 = MFMA32(xa, w1af[1], z, 0, 0, 0);
        f32x4 aA2 = MFMA32(xa, w1af[2], z, 0, 0, 0);
        f32x4 aA3 = MFMA32(xa, w1af[3], z, 0, 0, 0);
        f32x4 aB0 = MFMA32(xa, w1bf[0], z, 0, 0, 0);
        f32x4 aB1 = MFMA32(xa, w1bf[1], z, 0, 0, 0);
        f32x4 aB2 = MFMA32(xa, w1bf[2], z, 0, 0, 0);
        f32x4 aB3 = MFMA32(xa, w1bf[3], z, 0, 0, 0);
        #pragma unroll
        for (int reg = 0; reg < 4; ++reg){
            const int p = w * 16 + g4 * 4 + reg;
            if (p < 60){
                ss[A_S + p * 72 +      lane15] = bits16(aA0[reg] + b1v[0]);
                ss[A_S + p * 72 + 16 + lane15] = bits16(aA1[reg] + b1v[1]);
                ss[A_S + p * 72 + 32 + lane15] = bits16(aA2[reg] + b1v[2]);
                ss[A_S + p * 72 + 48 + lane15] = bits16(aA3[reg] + b1v[3]);
                ss[B_S + p * 72 +      lane15] = bits16(aB0[reg]);
                ss[B_S + p * 72 + 16 + lane15] = bits16(aB1[reg]);
                ss[B_S + p * 72 + 32 + lane15] = bits16(aB2[reg]);
                ss[B_S + p * 72 + 48 + lane15] = bits16(aB3[reg]);
            }
        }
    }
    __syncthreads();

    // ---- phase 2: swapped register chain. wave w owns receivers r = w, w+4, ... ----
    {
        // W2^T A-frags (16x16x32): row = h_out, k = h_in (k=60 row carries b2; row60 = 1-carry)
        bf16x8 w2tf[4][2];
        #pragma unroll
        for (int m = 0; m < 4; ++m){
            const int row = m * 16 + lane15;
            #pragma unroll
            for (int c2 = 0; c2 < 2; ++c2){
                #pragma unroll
                for (int j = 0; j < 8; ++j){
                    const int k = c2 * 32 + g4 * 8 + j;
                    float v = 0.f;
                    if (row < 60)      v = (k < 60) ? fr_w2[k * 60 + row] : (k == 60 ? fr_b2[row] : 0.f);
                    else if (row == 60) v = (k == 60) ? 1.f : 0.f;
                    w2tf[m][c2][j] = (__bf16)v;
                }
            }
        }
        // W3^T A-frags (16x16x16): row = e_out, k = h_out (k=60 carries b3)
        bf16x4 w3tf[2][4];
        #pragma unroll
        for (int m2 = 0; m2 < 2; ++m2){
            const int e = m2 * 16 + lane15;
            #pragma unroll
            for (int c = 0; c < 4; ++c){
                #pragma unroll
                for (int j = 0; j < 4; ++j){
                    const int k = c * 16 + g4 * 4 + j;
                    float v = 0.f;
                    if (e < 20) v = (k < 60) ? fr_w3[k * 20 + e] : (k == 60 ? fr_b3[e] : 0.f);
                    w3tf[m2][c][j] = (__bf16)v;
                }
            }
        }

        #pragma unroll 1
        for (int r = w; r < 60; r += 4){
            const u32x4 a0 = *(const u32x4*)&ss[A_S + r * 72 + g4 * 8];
            const u32x4 a1 = *(const u32x4*)&ss[A_S + r * 72 + 32 + g4 * 8];
            f32x4 acc0 = {0.f,0.f,0.f,0.f}, acc1 = {0.f,0.f,0.f,0.f};
            #pragma unroll
            for (int st = 0; st < 4; ++st){
                const int s = st * 16 + lane15;
                const u32x4 bb0 = *(const u32x4*)&ss[B_S + s * 72 + g4 * 8];
                const u32x4 bb1 = *(const u32x4*)&ss[B_S + s * 72 + 32 + g4 * 8];
                const bf16x8 h0 = addrelu(a0, bb0);
                const bf16x8 h1 = addrelu(a1, bb1);
                // layer 2: h2^T tiles m=0..3 (full-rate K=32)
                f32x4 d0 = {0.f,0.f,0.f,0.f}, d1 = {0.f,0.f,0.f,0.f};
                f32x4 d2 = {0.f,0.f,0.f,0.f}, d3 = {0.f,0.f,0.f,0.f};
                d0 = MFMA32(w2tf[0][0], h0, d0, 0,0,0); d0 = MFMA32(w2tf[0][1], h1, d0, 0,0,0);
                d1 = MFMA32(w2tf[1][0], h0, d1, 0,0,0); d1 = MFMA32(w2tf[1][1], h1, d1, 0,0,0);
                d2 = MFMA32(w2tf[2][0], h0, d2, 0,0,0); d2 = MFMA32(w2tf[2][1], h1, d2, 0,0,0);
                d3 = MFMA32(w2tf[3][0], h0, d3, 0,0,0); d3 = MFMA32(w2tf[3][1], h1, d3, 0,0,0);
                // junction: D regs ARE next B-frags (K=16 chain), relu+pack only
                const bf16x4 hb0 = relupack(d0), hb1 = relupack(d1);
                const bf16x4 hb2 = relupack(d2), hb3 = relupack(d3);
                // layer 3: E^T
                f32x4 e0 = {0.f,0.f,0.f,0.f}, e1 = {0.f,0.f,0.f,0.f};
                e0 = mfma_k16(w3tf[0][0], hb0, e0); e0 = mfma_k16(w3tf[0][1], hb1, e0);
                e0 = mfma_k16(w3tf[0][2], hb2, e0); e0 = mfma_k16(w3tf[0][3], hb3, e0);
                e1 = mfma_k16(w3tf[1][0], hb0, e1); e1 = mfma_k16(w3tf[1][1], hb1, e1);
                e1 = mfma_k16(w3tf[1][2], hb2, e1); e1 = mfma_k16(w3tf[1][3], hb3, e1);
                // relu + mask (pad cols & diagonal) + accumulate over s
                const float vm = (s < 60 && s != r) ? 1.f : 0.f;
                #pragma unroll
                for (int reg = 0; reg < 4; ++reg){
                    acc0[reg] += vm * fmaxf(e0[reg], 0.f);
                    acc1[reg] += vm * fmaxf(e1[reg], 0.f);
                }
            }
            // reduce over the 16 pair-lanes; wave owns r -> plain LDS add
            #pragma unroll
            for (int reg = 0; reg < 4; ++reg){
                float v0 = acc0[reg];
                v0 += __shfl_xor(v0, 1); v0 += __shfl_xor(v0, 2);
                v0 += __shfl_xor(v0, 4); v0 += __shfl_xor(v0, 8);
                float v1 = acc1[reg];
                v1 += __shfl_xor(v1, 1); v1 += __shfl_xor(v1, 2);
                v1 += __shfl_xor(v1, 4); v1 += __shfl_xor(v1, 8);
                if (lane15 == 0){
                    sf[EB_F + r * 20 + g4 * 4 + reg] += v0;
                    const int e1i = 16 + g4 * 4 + reg;
                    if (e1i < 20) sf[EB_F + r * 20 + e1i] += v1;
                }
            }
        }
    }
    __syncthreads();

    // ---- phase 5: output MLP, swapped chain. wave w = particle tile w ----
    {
        const int p5 = w * 16 + lane15;
        const int pe = (p5 < 60) ? p5 : 0;
        // C^T B-frags: k = [x(30), Ebar(20), 1, pad]
        const u32x4 uc0 = *(const u32x4*)&ss[XT_S + pe * 40 + g4 * 8];
        bf16x8 cb0 = __builtin_bit_cast(bf16x8, uc0);
        if (g4 == 3){
            cb0[6] = (__bf16)sf[EB_F + pe * 20 + 0];
            cb0[7] = (__bf16)sf[EB_F + pe * 20 + 1];
        }
        bf16x8 cb1;
        #pragma unroll
        for (int j = 0; j < 8; ++j){
            const int k = 32 + g4 * 8 + j;
            float v;
            if (k < 50) v = sf[EB_F + pe * 20 + (k - 30)];
            else        v = (k == 50) ? 1.f : 0.f;
            cb1[j] = (__bf16)v;
        }
        // L1 (16x16x32): W1o^T row=h, k=C-dim (k=50 carries b1; row60 = 1-row)
        bf16x8 w1of[4][2];
        #pragma unroll
        for (int m = 0; m < 4; ++m){
            const int h = m * 16 + lane15;
            #pragma unroll
            for (int c2 = 0; c2 < 2; ++c2){
                #pragma unroll
                for (int j = 0; j < 8; ++j){
                    const int k = c2 * 32 + g4 * 8 + j;
                    float v = 0.f;
                    if (h < 60)      v = (k < 50) ? fo_w1[k * 60 + h] : (k == 50 ? fo_b1[h] : 0.f);
                    else if (h == 60) v = (k == 50) ? 1.f : 0.f;
                    w1of[m][c2][j] = (__bf16)v;
                }
            }
        }
        f32x4 d0 = {0.f,0.f,0.f,0.f}, d1 = {0.f,0.f,0.f,0.f};
        f32x4 d2 = {0.f,0.f,0.f,0.f}, d3 = {0.f,0.f,0.f,0.f};
        d0 = MFMA32(w1of[0][0], cb0, d0, 0,0,0); d0 = MFMA32(w1of[0][1], cb1, d0, 0,0,0);
        d1 = MFMA32(w1of[1][0], cb0, d1, 0,0,0); d1 = MFMA32(w1of[1][1], cb1, d1, 0,0,0);
        d2 = MFMA32(w1of[2][0], cb0, d2, 0,0,0); d2 = MFMA32(w1of[2][1], cb1, d2, 0,0,0);
        d3 = MFMA32(w1of[3][0], cb0, d3, 0,0,0); d3 = MFMA32(w1of[3][1], cb1, d3, 0,0,0);
        const bf16x4 hb0 = relupack(d0), hb1 = relupack(d1);
        const bf16x4 hb2 = relupack(d2), hb3 = relupack(d3);
        // L2 (K=16 chain): W2o^T (k=60 carries b2; row60 = 1-row)
        bf16x4 w2of[4][4];
        #pragma unroll
        for (int m = 0; m < 4; ++m){
            const int h2 = m * 16 + lane15;
            #pragma unroll
            for (int c = 0; c < 4; ++c){
                #pragma unroll
                for (int j = 0; j < 4; ++j){
                    const int k = c * 16 + g4 * 4 + j;
                    float v = 0.f;
                    if (h2 < 60)      v = (k < 60) ? fo_w2[k * 60 + h2] : (k == 60 ? fo_b2[h2] : 0.f);
                    else if (h2 == 60) v = (k == 60) ? 1.f : 0.f;
                    w2of[m][c][j] = (__bf16)v;
                }
            }
        }
        f32x4 g0 = {0.f,0.f,0.f,0.f}, g1 = {0.f,0.f,0.f,0.f};
        f32x4 g2 = {0.f,0.f,0.f,0.f}, g3 = {0.f,0.f,0.f,0.f};
        g0 = mfma_k16(w2of[0][0], hb0, g0); g0 = mfma_k16(w2of[0][1], hb1, g0);
        g0 = mfma_k16(w2of[0][2], hb2, g0); g0 = mfma_k16(w2of[0][3], hb3, g0);
        g1 = mfma_k16(w2of[1][0], hb0, g1); g1 = mfma_k16(w2of[1][1], hb1, g1);
        g1 = mfma_k16(w2of[1][2], hb2, g1); g1 = mfma_k16(w2of[1][3], hb3, g1);
        g2 = mfma_k16(w2of[2][0], hb0, g2); g2 = mfma_k16(w2of[2][1], hb1, g2);
        g2 = mfma_k16(w2of[2][2], hb2, g2); g2 = mfma_k16(w2of[2][3], hb3, g2);
        g3 = mfma_k16(w2of[3][0], hb0, g3); g3 = mfma_k16(w2of[3][1], hb1, g3);
        g3 = mfma_k16(w2of[3][2], hb2, g3); g3 = mfma_k16(w2of[3][3], hb3, g3);
        const bf16x4 gb0 = relupack(g0), gb1 = relupack(g1);
        const bf16x4 gb2 = relupack(g2), gb3 = relupack(g3);
        // L3: W3o^T (k=60 carries b3)
        bf16x4 w3of[2][4];
        #pragma unroll
        for (int m2 = 0; m2 < 2; ++m2){
            const int o = m2 * 16 + lane15;
            #pragma unroll
            for (int c = 0; c < 4; ++c){
                #pragma unroll
                for (int j = 0; j < 4; ++j){
                    const int k = c * 16 + g4 * 4 + j;
                    float v = 0.f;
                    if (o < 24) v = (k < 60) ? fo_w3[k * 24 + o] : (k == 60 ? fo_b3[o] : 0.f);
                    w3of[m2][c][j] = (__bf16)v;
                }
            }
        }
        f32x4 o0 = {0.f,0.f,0.f,0.f}, o1 = {0.f,0.f,0.f,0.f};
        o0 = mfma_k16(w3of[0][0], gb0, o0); o0 = mfma_k16(w3of[0][1], gb1, o0);
        o0 = mfma_k16(w3of[0][2], gb2, o0); o0 = mfma_k16(w3of[0][3], gb3, o0);
        o1 = mfma_k16(w3of[1][0], gb0, o1); o1 = mfma_k16(w3of[1][1], gb1, o1);
        o1 = mfma_k16(w3of[1][2], gb2, o1); o1 = mfma_k16(w3of[1][3], gb3, o1);
        // relu + particle mask + reduce over 16 particle-lanes -> O
        const float vm = (p5 < 60) ? 1.f : 0.f;
        #pragma unroll
        for (int reg = 0; reg < 4; ++reg){
            float v0 = vm * fmaxf(o0[reg], 0.f);
            v0 += __shfl_xor(v0, 1); v0 += __shfl_xor(v0, 2);
            v0 += __shfl_xor(v0, 4); v0 += __shfl_xor(v0, 8);
            float v1 = vm * fmaxf(o1[reg], 0.f);
            v1 += __shfl_xor(v1, 1); v1 += __shfl_xor(v1, 2);
            v1 += __shfl_xor(v1, 4); v1 += __shfl_xor(v1, 8);
            if (lane15 == 0){
                atomicAdd(&sf[O_F + g4 * 4 + reg], v0);
                const int oi = 16 + g4 * 4 + reg;
                if (oi < 24) atomicAdd(&sf[O_F + oi], v1);
            }
        }
    }
    __syncthreads();
    if (tid < 24) out[(size_t)b * 24 + tid] = sf[O_F + tid];
}

extern "C" void kernel_launch(void* const* d_in, const int* in_sizes, int n_in,
                              void* d_out, int out_size, void* d_ws, size_t ws_size,
                              hipStream_t stream) {
    const float* x      = (const float*)d_in[0];
    const float* fr_w1  = (const float*)d_in[1];
    const float* fr_b1  = (const float*)d_in[2];
    const float* fr_w2  = (const float*)d_in[3];
    const float* fr_b2  = (const float*)d_in[4];
    const float* fr_w3  = (const float*)d_in[5];
    const float* fr_b3  = (const float*)d_in[6];
    const float* fo_w1  = (const float*)d_in[7];
    const float* fo_b1  = (const float*)d_in[8];
    const float* fo_w2  = (const float*)d_in[9];
    const float* fo_b2  = (const float*)d_in[10];
    const float* fo_w3  = (const float*)d_in[11];
    const float* fo_b3  = (const float*)d_in[12];
    float* out = (float*)d_out;

    const int B = in_sizes[0] / 1800;
    innet_kernel<<<dim3(B), dim3(256), 0, stream>>>(
        x, fr_w1, fr_b1, fr_w2, fr_b2, fr_w3, fr_b3,
        fo_w1, fo_b1, fo_w2, fo_b2, fo_w3, fo_b3, out);
}

// Round 10
// 212.431 us; speedup vs baseline: 1.5709x; 1.1734x over previous
//
#include <hip/hip_runtime.h>

typedef _Float16 f16x8 __attribute__((ext_vector_type(8)));
typedef _Float16 f16x4 __attribute__((ext_vector_type(4)));
typedef float  f32x4  __attribute__((ext_vector_type(4)));
typedef unsigned int u32x4 __attribute__((ext_vector_type(4)));
typedef unsigned int u32x2 __attribute__((ext_vector_type(2)));

#define MFMA32F __builtin_amdgcn_mfma_f32_16x16x32_f16

// K=16 f16 MFMA, hazard-safe
__device__ __forceinline__ f32x4 mfma_k16(const f16x4& a, const f16x4& b, f32x4 c){
#if __has_builtin(__builtin_amdgcn_mfma_f32_16x16x16f16)
    return __builtin_amdgcn_mfma_f32_16x16x16f16(a, b, c, 0, 0, 0);
#else
    asm volatile("s_nop 1\n\t"
                 "v_mfma_f32_16x16x16_f16 %0, %1, %2, %0\n\t"
                 "s_nop 7\n\t"
                 "s_nop 7"
                 : "+v"(c)
                 : "v"(__builtin_bit_cast(u32x2, a)), "v"(__builtin_bit_cast(u32x2, b)));
    return c;
#endif
}

// ---- LDS layout ----
// short indices:
#define XT_S 0        // Xt[60][40] f16 (cols 30..39 zero)
#define A_S  2400     // A[64][72] f16 (col60=1.0, 61..63=0, rows 60..63=0)
#define B_S  7008     // B[64][72] f16 (cols 60..63=0, rows 60..63=0)
// float indices:
#define EB_F 5808     // Ebar[60][20] f32   (short 11616)
#define O_F  7008     // O[24] f32
#define NSH  14064    // 28128 B

__device__ __forceinline__ unsigned short hbits(float x){ return __builtin_bit_cast(unsigned short, (_Float16)x); }

__device__ __forceinline__ f16x8 addrelu16(u32x4 a, u32x4 b){
    f16x8 s = __builtin_bit_cast(f16x8, a) + __builtin_bit_cast(f16x8, b);
    const f16x8 z = {};
    return __builtin_elementwise_max(s, z);   // v_pk_add_f16 + v_pk_max_f16
}

__device__ __forceinline__ f16x4 relupack16(const f32x4& d){
    f16x4 o;
    o[0] = (_Float16)fmaxf(d[0], 0.f);
    o[1] = (_Float16)fmaxf(d[1], 0.f);
    o[2] = (_Float16)fmaxf(d[2], 0.f);
    o[3] = (_Float16)fmaxf(d[3], 0.f);
    return o;
}

__global__ __launch_bounds__(256, 2)
void innet_kernel(const float* __restrict__ x,
                  const float* __restrict__ fr_w1, const float* __restrict__ fr_b1,
                  const float* __restrict__ fr_w2, const float* __restrict__ fr_b2,
                  const float* __restrict__ fr_w3, const float* __restrict__ fr_b3,
                  const float* __restrict__ fo_w1, const float* __restrict__ fo_b1,
                  const float* __restrict__ fo_w2, const float* __restrict__ fo_b2,
                  const float* __restrict__ fo_w3, const float* __restrict__ fo_b3,
                  float* __restrict__ out)
{
    __shared__ __align__(16) unsigned short ss[NSH];
    float* sf = (float*)ss;

    const int b      = blockIdx.x;
    const int tid    = threadIdx.x;
    const int lane15 = tid & 15;
    const int g4     = (tid >> 4) & 3;
    const int w      = tid >> 6;

    // ---- phase 0: stage x -> Xt f16 [p][f]; zero pads / EB / O ----
    const float* xb = x + b * 1800;
    for (int i = tid; i < 1800; i += 256){
        const int f = i / 60, p = i - f * 60;
        ss[XT_S + p * 40 + f] = hbits(xb[i]);
    }
    for (int i = tid; i < 600; i += 256){
        const int p = i / 10;
        ss[XT_S + p * 40 + 30 + (i - p * 10)] = 0;
    }
    for (int i = tid; i < 576; i += 256){           // panel rows 60..63 = 0
        const int arr = i / 288, rem = i - arr * 288;
        ss[(arr ? B_S : A_S) + 60 * 72 + rem] = 0;
    }
    for (int i = tid; i < 1200; i += 256) sf[EB_F + i] = 0.f;
    if (tid < 24) sf[O_F + tid] = 0.f;
    __syncthreads();

    // ---- phase 1: A/B panels via MFMA (16x16x32 f16). wave w = rows [16w,16w+16) ----
    {
        f16x8 w1af[4], w1bf[4];
        float b1v[4];
        #pragma unroll
        for (int n = 0; n < 4; ++n){
            const int col = n * 16 + lane15;
            const bool cvv = col < 60;
            b1v[n] = cvv ? fr_b1[col] : ((col == 60) ? 1.0f : 0.0f);  // col60 of A = bias-1
            #pragma unroll
            for (int j = 0; j < 8; ++j){
                const int f = g4 * 8 + j;
                w1af[n][j] = (_Float16)((f < 30 && cvv) ? fr_w1[f * 60 + col] : 0.f);
                w1bf[n][j] = (_Float16)((f < 30 && cvv) ? fr_w1[(30 + f) * 60 + col] : 0.f);
            }
        }
        const int pr_ = w * 16 + lane15;
        const u32x4 ux = *(const u32x4*)&ss[XT_S + pr_ * 40 + g4 * 8];
        const f16x8 xa = __builtin_bit_cast(f16x8, ux);
        const f32x4 z = {0.f, 0.f, 0.f, 0.f};
        f32x4 aA0 = MFMA32F(xa, w1af[0], z, 0, 0, 0);
        f32x4 aA1 = MFMA32F(xa, w1af[1], z, 0, 0, 0);
        f32x4 aA2 = MFMA32F(xa, w1af[2], z, 0, 0, 0);
        f32x4 aA3 = MFMA32F(xa, w1af[3], z, 0, 0, 0);
        f32x4 aB0 = MFMA32F(xa, w1bf[0], z, 0, 0, 0);
        f32x4 aB1 = MFMA32F(xa, w1bf[1], z, 0, 0, 0);
        f32x4 aB2 = MFMA32F(xa, w1bf[2], z, 0, 0, 0);
        f32x4 aB3 = MFMA32F(xa, w1bf[3], z, 0, 0, 0);
        #pragma unroll
        for (int reg = 0; reg < 4; ++reg){
            const int p = w * 16 + g4 * 4 + reg;
            if (p < 60){
                ss[A_S + p * 72 +      lane15] = hbits(aA0[reg] + b1v[0]);
                ss[A_S + p * 72 + 16 + lane15] = hbits(aA1[reg] + b1v[1]);
                ss[A_S + p * 72 + 32 + lane15] = hbits(aA2[reg] + b1v[2]);
                ss[A_S + p * 72 + 48 + lane15] = hbits(aA3[reg] + b1v[3]);
                ss[B_S + p * 72 +      lane15] = hbits(aB0[reg]);
                ss[B_S + p * 72 + 16 + lane15] = hbits(aB1[reg]);
                ss[B_S + p * 72 + 32 + lane15] = hbits(aB2[reg]);
                ss[B_S + p * 72 + 48 + lane15] = hbits(aB3[reg]);
            }
        }
    }
    __syncthreads();

    // ---- phase 2: swapped register chain. wave w owns receivers r = w, w+4, ... ----
    {
        // W2^T A-frags (16x16x32): row = h_out, k = h_in (k=60 carries b2; row60 = 1-carry)
        f16x8 w2tf[4][2];
        #pragma unroll
        for (int m = 0; m < 4; ++m){
            const int row = m * 16 + lane15;
            #pragma unroll
            for (int c2 = 0; c2 < 2; ++c2){
                #pragma unroll
                for (int j = 0; j < 8; ++j){
                    const int k = c2 * 32 + g4 * 8 + j;
                    float v = 0.f;
                    if (row < 60)      v = (k < 60) ? fr_w2[k * 60 + row] : (k == 60 ? fr_b2[row] : 0.f);
                    else if (row == 60) v = (k == 60) ? 1.f : 0.f;
                    w2tf[m][c2][j] = (_Float16)v;
                }
            }
        }
        // W3^T A-frags (16x16x16): row = e_out, k = h_out (k=60 carries b3)
        f16x4 w3tf[2][4];
        #pragma unroll
        for (int m2 = 0; m2 < 2; ++m2){
            const int e = m2 * 16 + lane15;
            #pragma unroll
            for (int c = 0; c < 4; ++c){
                #pragma unroll
                for (int j = 0; j < 4; ++j){
                    const int k = c * 16 + g4 * 4 + j;
                    float v = 0.f;
                    if (e < 20) v = (k < 60) ? fr_w3[k * 20 + e] : (k == 60 ? fr_b3[e] : 0.f);
                    w3tf[m2][c][j] = (_Float16)v;
                }
            }
        }

        #pragma unroll 1
        for (int r = w; r < 60; r += 4){
            const u32x4 a0 = *(const u32x4*)&ss[A_S + r * 72 + g4 * 8];
            const u32x4 a1 = *(const u32x4*)&ss[A_S + r * 72 + 32 + g4 * 8];
            f32x4 acc0 = {0.f,0.f,0.f,0.f}, acc1 = {0.f,0.f,0.f,0.f};
            #pragma unroll
            for (int st = 0; st < 4; ++st){
                const int s = st * 16 + lane15;
                const u32x4 bb0 = *(const u32x4*)&ss[B_S + s * 72 + g4 * 8];
                const u32x4 bb1 = *(const u32x4*)&ss[B_S + s * 72 + 32 + g4 * 8];
                const f16x8 h0 = addrelu16(a0, bb0);
                const f16x8 h1 = addrelu16(a1, bb1);
                // layer 2: h2^T tiles m=0..3 (full-rate K=32)
                f32x4 d0 = {0.f,0.f,0.f,0.f}, d1 = {0.f,0.f,0.f,0.f};
                f32x4 d2 = {0.f,0.f,0.f,0.f}, d3 = {0.f,0.f,0.f,0.f};
                d0 = MFMA32F(w2tf[0][0], h0, d0, 0,0,0); d0 = MFMA32F(w2tf[0][1], h1, d0, 0,0,0);
                d1 = MFMA32F(w2tf[1][0], h0, d1, 0,0,0); d1 = MFMA32F(w2tf[1][1], h1, d1, 0,0,0);
                d2 = MFMA32F(w2tf[2][0], h0, d2, 0,0,0); d2 = MFMA32F(w2tf[2][1], h1, d2, 0,0,0);
                d3 = MFMA32F(w2tf[3][0], h0, d3, 0,0,0); d3 = MFMA32F(w2tf[3][1], h1, d3, 0,0,0);
                // junction: D regs ARE next B-frags (K=16 chain), relu+pack only
                const f16x4 hb0 = relupack16(d0), hb1 = relupack16(d1);
                const f16x4 hb2 = relupack16(d2), hb3 = relupack16(d3);
                // layer 3: E^T
                f32x4 e0 = {0.f,0.f,0.f,0.f}, e1 = {0.f,0.f,0.f,0.f};
                e0 = mfma_k16(w3tf[0][0], hb0, e0); e0 = mfma_k16(w3tf[0][1], hb1, e0);
                e0 = mfma_k16(w3tf[0][2], hb2, e0); e0 = mfma_k16(w3tf[0][3], hb3, e0);
                e1 = mfma_k16(w3tf[1][0], hb0, e1); e1 = mfma_k16(w3tf[1][1], hb1, e1);
                e1 = mfma_k16(w3tf[1][2], hb2, e1); e1 = mfma_k16(w3tf[1][3], hb3, e1);
                // relu + mask (pad cols & diagonal) + accumulate over s
                const float vm = (s < 60 && s != r) ? 1.f : 0.f;
                #pragma unroll
                for (int reg = 0; reg < 4; ++reg){
                    acc0[reg] += vm * fmaxf(e0[reg], 0.f);
                    acc1[reg] += vm * fmaxf(e1[reg], 0.f);
                }
            }
            // reduce over the 16 pair-lanes; wave owns r -> plain LDS add
            #pragma unroll
            for (int reg = 0; reg < 4; ++reg){
                float v0 = acc0[reg];
                v0 += __shfl_xor(v0, 1); v0 += __shfl_xor(v0, 2);
                v0 += __shfl_xor(v0, 4); v0 += __shfl_xor(v0, 8);
                float v1 = acc1[reg];
                v1 += __shfl_xor(v1, 1); v1 += __shfl_xor(v1, 2);
                v1 += __shfl_xor(v1, 4); v1 += __shfl_xor(v1, 8);
                if (lane15 == 0){
                    sf[EB_F + r * 20 + g4 * 4 + reg] += v0;
                    const int e1i = 16 + g4 * 4 + reg;
                    if (e1i < 20) sf[EB_F + r * 20 + e1i] += v1;
                }
            }
        }
    }
    __syncthreads();

    // ---- phase 5: output MLP, swapped chain. wave w = particle tile w ----
    {
        const int p5 = w * 16 + lane15;
        const int pe = (p5 < 60) ? p5 : 0;
        // C^T B-frags: k = [x(30), Ebar(20), 1, pad]
        const u32x4 uc0 = *(const u32x4*)&ss[XT_S + pe * 40 + g4 * 8];
        f16x8 cb0 = __builtin_bit_cast(f16x8, uc0);
        if (g4 == 3){
            cb0[6] = (_Float16)sf[EB_F + pe * 20 + 0];
            cb0[7] = (_Float16)sf[EB_F + pe * 20 + 1];
        }
        f16x8 cb1;
        #pragma unroll
        for (int j = 0; j < 8; ++j){
            const int k = 32 + g4 * 8 + j;
            float v;
            if (k < 50) v = sf[EB_F + pe * 20 + (k - 30)];
            else        v = (k == 50) ? 1.f : 0.f;
            cb1[j] = (_Float16)v;
        }
        // L1 (16x16x32): W1o^T row=h, k=C-dim (k=50 carries b1; row60 = 1-row)
        f16x8 w1of[4][2];
        #pragma unroll
        for (int m = 0; m < 4; ++m){
            const int h = m * 16 + lane15;
            #pragma unroll
            for (int c2 = 0; c2 < 2; ++c2){
                #pragma unroll
                for (int j = 0; j < 8; ++j){
                    const int k = c2 * 32 + g4 * 8 + j;
                    float v = 0.f;
                    if (h < 60)      v = (k < 50) ? fo_w1[k * 60 + h] : (k == 50 ? fo_b1[h] : 0.f);
                    else if (h == 60) v = (k == 50) ? 1.f : 0.f;
                    w1of[m][c2][j] = (_Float16)v;
                }
            }
        }
        f32x4 d0 = {0.f,0.f,0.f,0.f}, d1 = {0.f,0.f,0.f,0.f};
        f32x4 d2 = {0.f,0.f,0.f,0.f}, d3 = {0.f,0.f,0.f,0.f};
        d0 = MFMA32F(w1of[0][0], cb0, d0, 0,0,0); d0 = MFMA32F(w1of[0][1], cb1, d0, 0,0,0);
        d1 = MFMA32F(w1of[1][0], cb0, d1, 0,0,0); d1 = MFMA32F(w1of[1][1], cb1, d1, 0,0,0);
        d2 = MFMA32F(w1of[2][0], cb0, d2, 0,0,0); d2 = MFMA32F(w1of[2][1], cb1, d2, 0,0,0);
        d3 = MFMA32F(w1of[3][0], cb0, d3, 0,0,0); d3 = MFMA32F(w1of[3][1], cb1, d3, 0,0,0);
        const f16x4 hb0 = relupack16(d0), hb1 = relupack16(d1);
        const f16x4 hb2 = relupack16(d2), hb3 = relupack16(d3);
        __builtin_amdgcn_sched_barrier(0);   // keep w2of loads after L1 (register peak)
        // L2 (K=16 chain): W2o^T (k=60 carries b2; row60 = 1-row)
        f16x4 w2of[4][4];
        #pragma unroll
        for (int m = 0; m < 4; ++m){
            const int h2 = m * 16 + lane15;
            #pragma unroll
            for (int c = 0; c < 4; ++c){
                #pragma unroll
                for (int j = 0; j < 4; ++j){
                    const int k = c * 16 + g4 * 4 + j;
                    float v = 0.f;
                    if (h2 < 60)      v = (k < 60) ? fo_w2[k * 60 + h2] : (k == 60 ? fo_b2[h2] : 0.f);
                    else if (h2 == 60) v = (k == 60) ? 1.f : 0.f;
                    w2of[m][c][j] = (_Float16)v;
                }
            }
        }
        f32x4 g0 = {0.f,0.f,0.f,0.f}, g1 = {0.f,0.f,0.f,0.f};
        f32x4 g2 = {0.f,0.f,0.f,0.f}, g3 = {0.f,0.f,0.f,0.f};
        g0 = mfma_k16(w2of[0][0], hb0, g0); g0 = mfma_k16(w2of[0][1], hb1, g0);
        g0 = mfma_k16(w2of[0][2], hb2, g0); g0 = mfma_k16(w2of[0][3], hb3, g0);
        g1 = mfma_k16(w2of[1][0], hb0, g1); g1 = mfma_k16(w2of[1][1], hb1, g1);
        g1 = mfma_k16(w2of[1][2], hb2, g1); g1 = mfma_k16(w2of[1][3], hb3, g1);
        g2 = mfma_k16(w2of[2][0], hb0, g2); g2 = mfma_k16(w2of[2][1], hb1, g2);
        g2 = mfma_k16(w2of[2][2], hb2, g2); g2 = mfma_k16(w2of[2][3], hb3, g2);
        g3 = mfma_k16(w2of[3][0], hb0, g3); g3 = mfma_k16(w2of[3][1], hb1, g3);
        g3 = mfma_k16(w2of[3][2], hb2, g3); g3 = mfma_k16(w2of[3][3], hb3, g3);
        const f16x4 gb0 = relupack16(g0), gb1 = relupack16(g1);
        const f16x4 gb2 = relupack16(g2), gb3 = relupack16(g3);
        __builtin_amdgcn_sched_barrier(0);   // keep w3of loads after L2
        // L3: W3o^T (k=60 carries b3)
        f16x4 w3of[2][4];
        #pragma unroll
        for (int m2 = 0; m2 < 2; ++m2){
            const int o = m2 * 16 + lane15;
            #pragma unroll
            for (int c = 0; c < 4; ++c){
                #pragma unroll
                for (int j = 0; j < 4; ++j){
                    const int k = c * 16 + g4 * 4 + j;
                    float v = 0.f;
                    if (o < 24) v = (k < 60) ? fo_w3[k * 24 + o] : (k == 60 ? fo_b3[o] : 0.f);
                    w3of[m2][c][j] = (_Float16)v;
                }
            }
        }
        f32x4 o0 = {0.f,0.f,0.f,0.f}, o1 = {0.f,0.f,0.f,0.f};
        o0 = mfma_k16(w3of[0][0], gb0, o0); o0 = mfma_k16(w3of[0][1], gb1, o0);
        o0 = mfma_k16(w3of[0][2], gb2, o0); o0 = mfma_k16(w3of[0][3], gb3, o0);
        o1 = mfma_k16(w3of[1][0], gb0, o1); o1 = mfma_k16(w3of[1][1], gb1, o1);
        o1 = mfma_k16(w3of[1][2], gb2, o1); o1 = mfma_k16(w3of[1][3], gb3, o1);
        // relu + particle mask + reduce over 16 particle-lanes -> O
        const float vm = (p5 < 60) ? 1.f : 0.f;
        #pragma unroll
        for (int reg = 0; reg < 4; ++reg){
            float v0 = vm * fmaxf(o0[reg], 0.f);
            v0 += __shfl_xor(v0, 1); v0 += __shfl_xor(v0, 2);
            v0 += __shfl_xor(v0, 4); v0 += __shfl_xor(v0, 8);
            float v1 = vm * fmaxf(o1[reg], 0.f);
            v1 += __shfl_xor(v1, 1); v1 += __shfl_xor(v1, 2);
            v1 += __shfl_xor(v1, 4); v1 += __shfl_xor(v1, 8);
            if (lane15 == 0){
                atomicAdd(&sf[O_F + g4 * 4 + reg], v0);
                const int oi = 16 + g4 * 4 + reg;
                if (oi < 24) atomicAdd(&sf[O_F + oi], v1);
            }
        }
    }
    __syncthreads();
    if (tid < 24) out[(size_t)b * 24 + tid] = sf[O_F + tid];
}

extern "C" void kernel_launch(void* const* d_in, const int* in_sizes, int n_in,
                              void* d_out, int out_size, void* d_ws, size_t ws_size,
                              hipStream_t stream) {
    const float* x      = (const float*)d_in[0];
    const float* fr_w1  = (const float*)d_in[1];
    const float* fr_b1  = (const float*)d_in[2];
    const float* fr_w2  = (const float*)d_in[3];
    const float* fr_b2  = (const float*)d_in[4];
    const float* fr_w3  = (const float*)d_in[5];
    const float* fr_b3  = (const float*)d_in[6];
    const float* fo_w1  = (const float*)d_in[7];
    const float* fo_b1  = (const float*)d_in[8];
    const float* fo_w2  = (const float*)d_in[9];
    const float* fo_b2  = (const float*)d_in[10];
    const float* fo_w3  = (const float*)d_in[11];
    const float* fo_b3  = (const float*)d_in[12];
    float* out = (float*)d_out;

    const int B = in_sizes[0] / 1800;
    innet_kernel<<<dim3(B), dim3(256), 0, stream>>>(
        x, fr_w1, fr_b1, fr_w2, fr_b2, fr_w3, fr_b3,
        fo_w1, fo_b1, fo_w2, fo_b2, fo_w3, fo_b3, out);
}

// Round 12
// 159.786 us; speedup vs baseline: 2.0885x; 1.3295x over previous
//
#include <hip/hip_runtime.h>

typedef _Float16 f16x8 __attribute__((ext_vector_type(8)));
typedef _Float16 f16x4 __attribute__((ext_vector_type(4)));
typedef float  f32x4  __attribute__((ext_vector_type(4)));
typedef unsigned int u32x4 __attribute__((ext_vector_type(4)));
typedef unsigned int u32x2 __attribute__((ext_vector_type(2)));

#define MFMA32F __builtin_amdgcn_mfma_f32_16x16x32_f16

// K=16 f16 MFMA, hazard-safe
__device__ __forceinline__ f32x4 mfma_k16(const f16x4& a, const f16x4& b, f32x4 c){
#if __has_builtin(__builtin_amdgcn_mfma_f32_16x16x16f16)
    return __builtin_amdgcn_mfma_f32_16x16x16f16(a, b, c, 0, 0, 0);
#else
    asm volatile("s_nop 1\n\t"
                 "v_mfma_f32_16x16x16_f16 %0, %1, %2, %0\n\t"
                 "s_nop 7\n\t"
                 "s_nop 7"
                 : "+v"(c)
                 : "v"(__builtin_bit_cast(u32x2, a)), "v"(__builtin_bit_cast(u32x2, b)));
    return c;
#endif
}

// ---- LDS layout ----
// short indices:
#define XT_S 0        // Xt[60][40] f16 (cols 30..39 zero)
#define A_S  2400     // A[64][72] f16 (col60=1.0, 61..63=0, rows 60..63=0)
#define B_S  7008     // B[64][72] f16 (cols 60..63=0, rows 60..63=0)
// float indices:
#define EB_F 5808     // Ebar[60][20] f32   (short 11616)
#define O_F  7008     // O[24] f32
#define NSH  14064    // 28128 B

__device__ __forceinline__ unsigned short hbits(float x){ return __builtin_bit_cast(unsigned short, (_Float16)x); }

__device__ __forceinline__ f16x8 addrelu16(u32x4 a, u32x4 b){
    f16x8 s = __builtin_bit_cast(f16x8, a) + __builtin_bit_cast(f16x8, b);
    const f16x8 z = {};
    return __builtin_elementwise_max(s, z);   // v_pk_add_f16 + v_pk_max_f16
}

// f32x4 -> f16x4 with relu: 2x v_cvt_pkrtz_f16_f32 + packed max
__device__ __forceinline__ f16x4 relupack16(const f32x4& d){
    u32x2 u;
    u[0] = __builtin_bit_cast(unsigned int, __builtin_amdgcn_cvt_pkrtz(d[0], d[1]));
    u[1] = __builtin_bit_cast(unsigned int, __builtin_amdgcn_cvt_pkrtz(d[2], d[3]));
    const f16x4 z = {};
    return __builtin_elementwise_max(__builtin_bit_cast(f16x4, u), z);
}

__global__ __launch_bounds__(256, 3)
void innet_kernel(const float* __restrict__ x,
                  const float* __restrict__ fr_w1, const float* __restrict__ fr_b1,
                  const float* __restrict__ fr_w2, const float* __restrict__ fr_b2,
                  const float* __restrict__ fr_w3, const float* __restrict__ fr_b3,
                  const float* __restrict__ fo_w1, const float* __restrict__ fo_b1,
                  const float* __restrict__ fo_w2, const float* __restrict__ fo_b2,
                  const float* __restrict__ fo_w3, const float* __restrict__ fo_b3,
                  float* __restrict__ out)
{
    __shared__ __align__(16) unsigned short ss[NSH];
    float* sf = (float*)ss;

    const int b      = blockIdx.x;
    const int tid    = threadIdx.x;
    const int lane15 = tid & 15;
    const int g4     = (tid >> 4) & 3;
    const int w      = tid >> 6;

    // ---- phase 0: stage x -> Xt f16 [p][f]; zero pads / EB / O ----
    const float* xb = x + b * 1800;
    for (int i = tid; i < 1800; i += 256){
        const int f = i / 60, p = i - f * 60;
        ss[XT_S + p * 40 + f] = hbits(xb[i]);
    }
    for (int i = tid; i < 600; i += 256){
        const int p = i / 10;
        ss[XT_S + p * 40 + 30 + (i - p * 10)] = 0;
    }
    for (int i = tid; i < 576; i += 256){           // panel rows 60..63 = 0
        const int arr = i / 288, rem = i - arr * 288;
        ss[(arr ? B_S : A_S) + 60 * 72 + rem] = 0;
    }
    for (int i = tid; i < 1200; i += 256) sf[EB_F + i] = 0.f;
    if (tid < 24) sf[O_F + tid] = 0.f;
    __syncthreads();

    // ---- phase 1: A/B panels via MFMA (16x16x32 f16). wave w = rows [16w,16w+16) ----
    {
        f16x8 w1af[4], w1bf[4];
        float b1v[4];
        #pragma unroll
        for (int n = 0; n < 4; ++n){
            const int col = n * 16 + lane15;
            const bool cvv = col < 60;
            b1v[n] = cvv ? fr_b1[col] : ((col == 60) ? 1.0f : 0.0f);  // col60 of A = bias-1
            #pragma unroll
            for (int j = 0; j < 8; ++j){
                const int f = g4 * 8 + j;
                w1af[n][j] = (_Float16)((f < 30 && cvv) ? fr_w1[f * 60 + col] : 0.f);
                w1bf[n][j] = (_Float16)((f < 30 && cvv) ? fr_w1[(30 + f) * 60 + col] : 0.f);
            }
        }
        const int pr_ = w * 16 + lane15;
        const u32x4 ux = *(const u32x4*)&ss[XT_S + pr_ * 40 + g4 * 8];
        const f16x8 xa = __builtin_bit_cast(f16x8, ux);
        const f32x4 z = {0.f, 0.f, 0.f, 0.f};
        f32x4 aA0 = MFMA32F(xa, w1af[0], z, 0, 0, 0);
        f32x4 aA1 = MFMA32F(xa, w1af[1], z, 0, 0, 0);
        f32x4 aA2 = MFMA32F(xa, w1af[2], z, 0, 0, 0);
        f32x4 aA3 = MFMA32F(xa, w1af[3], z, 0, 0, 0);
        f32x4 aB0 = MFMA32F(xa, w1bf[0], z, 0, 0, 0);
        f32x4 aB1 = MFMA32F(xa, w1bf[1], z, 0, 0, 0);
        f32x4 aB2 = MFMA32F(xa, w1bf[2], z, 0, 0, 0);
        f32x4 aB3 = MFMA32F(xa, w1bf[3], z, 0, 0, 0);
        #pragma unroll
        for (int reg = 0; reg < 4; ++reg){
            const int p = w * 16 + g4 * 4 + reg;
            if (p < 60){
                ss[A_S + p * 72 +      lane15] = hbits(aA0[reg] + b1v[0]);
                ss[A_S + p * 72 + 16 + lane15] = hbits(aA1[reg] + b1v[1]);
                ss[A_S + p * 72 + 32 + lane15] = hbits(aA2[reg] + b1v[2]);
                ss[A_S + p * 72 + 48 + lane15] = hbits(aA3[reg] + b1v[3]);
                ss[B_S + p * 72 +      lane15] = hbits(aB0[reg]);
                ss[B_S + p * 72 + 16 + lane15] = hbits(aB1[reg]);
                ss[B_S + p * 72 + 32 + lane15] = hbits(aB2[reg]);
                ss[B_S + p * 72 + 48 + lane15] = hbits(aB3[reg]);
            }
        }
    }
    __syncthreads();

    // ---- phase 2: swapped register chain. wave w owns receivers r = w, w+4, ... ----
    {
        // W2^T A-frags (16x16x32): row = h_out, k = h_in (k=60 carries b2; row60 = 1-carry)
        f16x8 w2tf[4][2];
        #pragma unroll
        for (int m = 0; m < 4; ++m){
            const int row = m * 16 + lane15;
            #pragma unroll
            for (int c2 = 0; c2 < 2; ++c2){
                #pragma unroll
                for (int j = 0; j < 8; ++j){
                    const int k = c2 * 32 + g4 * 8 + j;
                    float v = 0.f;
                    if (row < 60)      v = (k < 60) ? fr_w2[k * 60 + row] : (k == 60 ? fr_b2[row] : 0.f);
                    else if (row == 60) v = (k == 60) ? 1.f : 0.f;
                    w2tf[m][c2][j] = (_Float16)v;
                }
            }
        }
        // W3^T A-frags (16x16x16): row = e_out, k = h_out (k=60 carries b3)
        f16x4 w3tf[2][4];
        #pragma unroll
        for (int m2 = 0; m2 < 2; ++m2){
            const int e = m2 * 16 + lane15;
            #pragma unroll
            for (int c = 0; c < 4; ++c){
                #pragma unroll
                for (int j = 0; j < 4; ++j){
                    const int k = c * 16 + g4 * 4 + j;
                    float v = 0.f;
                    if (e < 20) v = (k < 60) ? fr_w3[k * 20 + e] : (k == 60 ? fr_b3[e] : 0.f);
                    w3tf[m2][c][j] = (_Float16)v;
                }
            }
        }

        #pragma unroll 1
        for (int r = w; r < 60; r += 4){
            const u32x4 a0 = *(const u32x4*)&ss[A_S + r * 72 + g4 * 8];
            const u32x4 a1 = *(const u32x4*)&ss[A_S + r * 72 + 32 + g4 * 8];
            f32x4 acc0 = {0.f,0.f,0.f,0.f}, acc1 = {0.f,0.f,0.f,0.f};
            #pragma unroll
            for (int st = 0; st < 4; ++st){
                const int s = st * 16 + lane15;
                const u32x4 bb0 = *(const u32x4*)&ss[B_S + s * 72 + g4 * 8];
                const u32x4 bb1 = *(const u32x4*)&ss[B_S + s * 72 + 32 + g4 * 8];
                const f16x8 h0 = addrelu16(a0, bb0);
                const f16x8 h1 = addrelu16(a1, bb1);
                // layer 2: h2^T tiles m=0..3 (full-rate K=32)
                f32x4 d0 = {0.f,0.f,0.f,0.f}, d1 = {0.f,0.f,0.f,0.f};
                f32x4 d2 = {0.f,0.f,0.f,0.f}, d3 = {0.f,0.f,0.f,0.f};
                d0 = MFMA32F(w2tf[0][0], h0, d0, 0,0,0); d0 = MFMA32F(w2tf[0][1], h1, d0, 0,0,0);
                d1 = MFMA32F(w2tf[1][0], h0, d1, 0,0,0); d1 = MFMA32F(w2tf[1][1], h1, d1, 0,0,0);
                d2 = MFMA32F(w2tf[2][0], h0, d2, 0,0,0); d2 = MFMA32F(w2tf[2][1], h1, d2, 0,0,0);
                d3 = MFMA32F(w2tf[3][0], h0, d3, 0,0,0); d3 = MFMA32F(w2tf[3][1], h1, d3, 0,0,0);
                // junction: D regs ARE next B-frags (K=16 chain), relu+pack only
                const f16x4 hb0 = relupack16(d0), hb1 = relupack16(d1);
                const f16x4 hb2 = relupack16(d2), hb3 = relupack16(d3);
                // layer 3: E^T
                f32x4 e0 = {0.f,0.f,0.f,0.f}, e1 = {0.f,0.f,0.f,0.f};
                e0 = mfma_k16(w3tf[0][0], hb0, e0); e0 = mfma_k16(w3tf[0][1], hb1, e0);
                e0 = mfma_k16(w3tf[0][2], hb2, e0); e0 = mfma_k16(w3tf[0][3], hb3, e0);
                e1 = mfma_k16(w3tf[1][0], hb0, e1); e1 = mfma_k16(w3tf[1][1], hb1, e1);
                e1 = mfma_k16(w3tf[1][2], hb2, e1); e1 = mfma_k16(w3tf[1][3], hb3, e1);
                // relu + mask (pad cols & diagonal) + accumulate over s
                const float vm = (s < 60 && s != r) ? 1.f : 0.f;
                #pragma unroll
                for (int reg = 0; reg < 4; ++reg){
                    acc0[reg] += vm * fmaxf(e0[reg], 0.f);
                    acc1[reg] += vm * fmaxf(e1[reg], 0.f);
                }
            }
            // reduce over the 16 pair-lanes; wave owns r -> plain LDS add
            #pragma unroll
            for (int reg = 0; reg < 4; ++reg){
                float v0 = acc0[reg];
                v0 += __shfl_xor(v0, 1); v0 += __shfl_xor(v0, 2);
                v0 += __shfl_xor(v0, 4); v0 += __shfl_xor(v0, 8);
                float v1 = acc1[reg];
                v1 += __shfl_xor(v1, 1); v1 += __shfl_xor(v1, 2);
                v1 += __shfl_xor(v1, 4); v1 += __shfl_xor(v1, 8);
                if (lane15 == 0){
                    sf[EB_F + r * 20 + g4 * 4 + reg] += v0;
                    const int e1i = 16 + g4 * 4 + reg;
                    if (e1i < 20) sf[EB_F + r * 20 + e1i] += v1;
                }
            }
        }
    }
    __syncthreads();

    // ---- phase 5: output MLP, swapped chain. wave w = particle tile w ----
    {
        const int p5 = w * 16 + lane15;
        const int pe = (p5 < 60) ? p5 : 0;
        // C^T B-frags: k = [x(30), Ebar(20), 1, pad]
        const u32x4 uc0 = *(const u32x4*)&ss[XT_S + pe * 40 + g4 * 8];
        f16x8 cb0 = __builtin_bit_cast(f16x8, uc0);
        if (g4 == 3){
            cb0[6] = (_Float16)sf[EB_F + pe * 20 + 0];
            cb0[7] = (_Float16)sf[EB_F + pe * 20 + 1];
        }
        f16x8 cb1;
        #pragma unroll
        for (int j = 0; j < 8; ++j){
            const int k = 32 + g4 * 8 + j;
            float v;
            if (k < 50) v = sf[EB_F + pe * 20 + (k - 30)];
            else        v = (k == 50) ? 1.f : 0.f;
            cb1[j] = (_Float16)v;
        }
        // L1 (16x16x32): W1o^T row=h, k=C-dim (k=50 carries b1; row60 = 1-row)
        f16x8 w1of[4][2];
        #pragma unroll
        for (int m = 0; m < 4; ++m){
            const int h = m * 16 + lane15;
            #pragma unroll
            for (int c2 = 0; c2 < 2; ++c2){
                #pragma unroll
                for (int j = 0; j < 8; ++j){
                    const int k = c2 * 32 + g4 * 8 + j;
                    float v = 0.f;
                    if (h < 60)      v = (k < 50) ? fo_w1[k * 60 + h] : (k == 50 ? fo_b1[h] : 0.f);
                    else if (h == 60) v = (k == 50) ? 1.f : 0.f;
                    w1of[m][c2][j] = (_Float16)v;
                }
            }
        }
        f32x4 d0 = {0.f,0.f,0.f,0.f}, d1 = {0.f,0.f,0.f,0.f};
        f32x4 d2 = {0.f,0.f,0.f,0.f}, d3 = {0.f,0.f,0.f,0.f};
        d0 = MFMA32F(w1of[0][0], cb0, d0, 0,0,0); d0 = MFMA32F(w1of[0][1], cb1, d0, 0,0,0);
        d1 = MFMA32F(w1of[1][0], cb0, d1, 0,0,0); d1 = MFMA32F(w1of[1][1], cb1, d1, 0,0,0);
        d2 = MFMA32F(w1of[2][0], cb0, d2, 0,0,0); d2 = MFMA32F(w1of[2][1], cb1, d2, 0,0,0);
        d3 = MFMA32F(w1of[3][0], cb0, d3, 0,0,0); d3 = MFMA32F(w1of[3][1], cb1, d3, 0,0,0);
        const f16x4 hb0 = relupack16(d0), hb1 = relupack16(d1);
        const f16x4 hb2 = relupack16(d2), hb3 = relupack16(d3);
        __builtin_amdgcn_sched_barrier(0);   // keep w2of loads after L1 (register peak)
        // L2 (K=16 chain): W2o^T (k=60 carries b2; row60 = 1-row)
        f16x4 w2of[4][4];
        #pragma unroll
        for (int m = 0; m < 4; ++m){
            const int h2 = m * 16 + lane15;
            #pragma unroll
            for (int c = 0; c < 4; ++c){
                #pragma unroll
                for (int j = 0; j < 4; ++j){
                    const int k = c * 16 + g4 * 4 + j;
                    float v = 0.f;
                    if (h2 < 60)      v = (k < 60) ? fo_w2[k * 60 + h2] : (k == 60 ? fo_b2[h2] : 0.f);
                    else if (h2 == 60) v = (k == 60) ? 1.f : 0.f;
                    w2of[m][c][j] = (_Float16)v;
                }
            }
        }
        f32x4 g0 = {0.f,0.f,0.f,0.f}, g1 = {0.f,0.f,0.f,0.f};
        f32x4 g2 = {0.f,0.f,0.f,0.f}, g3 = {0.f,0.f,0.f,0.f};
        g0 = mfma_k16(w2of[0][0], hb0, g0); g0 = mfma_k16(w2of[0][1], hb1, g0);
        g0 = mfma_k16(w2of[0][2], hb2, g0); g0 = mfma_k16(w2of[0][3], hb3, g0);
        g1 = mfma_k16(w2of[1][0], hb0, g1); g1 = mfma_k16(w2of[1][1], hb1, g1);
        g1 = mfma_k16(w2of[1][2], hb2, g1); g1 = mfma_k16(w2of[1][3], hb3, g1);
        g2 = mfma_k16(w2of[2][0], hb0, g2); g2 = mfma_k16(w2of[2][1], hb1, g2);
        g2 = mfma_k16(w2of[2][2], hb2, g2); g2 = mfma_k16(w2of[2][3], hb3, g2);
        g3 = mfma_k16(w2of[3][0], hb0, g3); g3 = mfma_k16(w2of[3][1], hb1, g3);
        g3 = mfma_k16(w2of[3][2], hb2, g3); g3 = mfma_k16(w2of[3][3], hb3, g3);
        const f16x4 gb0 = relupack16(g0), gb1 = relupack16(g1);
        const f16x4 gb2 = relupack16(g2), gb3 = relupack16(g3);
        __builtin_amdgcn_sched_barrier(0);   // keep w3of loads after L2
        // L3: W3o^T (k=60 carries b3)
        f16x4 w3of[2][4];
        #pragma unroll
        for (int m2 = 0; m2 < 2; ++m2){
            const int o = m2 * 16 + lane15;
            #pragma unroll
            for (int c = 0; c < 4; ++c){
                #pragma unroll
                for (int j = 0; j < 4; ++j){
                    const int k = c * 16 + g4 * 4 + j;
                    float v = 0.f;
                    if (o < 24) v = (k < 60) ? fo_w3[k * 24 + o] : (k == 60 ? fo_b3[o] : 0.f);
                    w3of[m2][c][j] = (_Float16)v;
                }
            }
        }
        f32x4 o0 = {0.f,0.f,0.f,0.f}, o1 = {0.f,0.f,0.f,0.f};
        o0 = mfma_k16(w3of[0][0], gb0, o0); o0 = mfma_k16(w3of[0][1], gb1, o0);
        o0 = mfma_k16(w3of[0][2], gb2, o0); o0 = mfma_k16(w3of[0][3], gb3, o0);
        o1 = mfma_k16(w3of[1][0], gb0, o1); o1 = mfma_k16(w3of[1][1], gb1, o1);
        o1 = mfma_k16(w3of[1][2], gb2, o1); o1 = mfma_k16(w3of[1][3], gb3, o1);
        // relu + particle mask + reduce over 16 particle-lanes -> O
        const float vm = (p5 < 60) ? 1.f : 0.f;
        #pragma unroll
        for (int reg = 0; reg < 4; ++reg){
            float v0 = vm * fmaxf(o0[reg], 0.f);
            v0 += __shfl_xor(v0, 1); v0 += __shfl_xor(v0, 2);
            v0 += __shfl_xor(v0, 4); v0 += __shfl_xor(v0, 8);
            float v1 = vm * fmaxf(o1[reg], 0.f);
            v1 += __shfl_xor(v1, 1); v1 += __shfl_xor(v1, 2);
            v1 += __shfl_xor(v1, 4); v1 += __shfl_xor(v1, 8);
            if (lane15 == 0){
                atomicAdd(&sf[O_F + g4 * 4 + reg], v0);
                const int oi = 16 + g4 * 4 + reg;
                if (oi < 24) atomicAdd(&sf[O_F + oi], v1);
            }
        }
    }
    __syncthreads();
    if (tid < 24) out[(size_t)b * 24 + tid] = sf[O_F + tid];
}

extern "C" void kernel_launch(void* const* d_in, const int* in_sizes, int n_in,
                              void* d_out, int out_size, void* d_ws, size_t ws_size,
                              hipStream_t stream) {
    const float* x      = (const float*)d_in[0];
    const float* fr_w1  = (const float*)d_in[1];
    const float* fr_b1  = (const float*)d_in[2];
    const float* fr_w2  = (const float*)d_in[3];
    const float* fr_b2  = (const float*)d_in[4];
    const float* fr_w3  = (const float*)d_in[5];
    const float* fr_b3  = (const float*)d_in[6];
    const float* fo_w1  = (const float*)d_in[7];
    const float* fo_b1  = (const float*)d_in[8];
    const float* fo_w2  = (const float*)d_in[9];
    const float* fo_b2  = (const float*)d_in[10];
    const float* fo_w3  = (const float*)d_in[11];
    const float* fo_b3  = (const float*)d_in[12];
    float* out = (float*)d_out;

    const int B = in_sizes[0] / 1800;
    innet_kernel<<<dim3(B), dim3(256), 0, stream>>>(
        x, fr_w1, fr_b1, fr_w2, fr_b2, fr_w3, fr_b3,
        fo_w1, fo_b1, fo_w2, fo_b2, fo_w3, fo_b3, out);
}